// Round 2
// baseline (464.021 us; speedup 1.0000x reference)
//
#include <hip/hip_runtime.h>
#include <hip/hip_bf16.h>
#include <math.h>

#define DIM   2048
#define NH    16
#define HD    128
#define SEQ   2048
#define BATCH 2
#define QKVN  6144   // 3*DIM

typedef __attribute__((ext_vector_type(8))) short short8;
typedef __attribute__((ext_vector_type(4))) float f32x4;
typedef __attribute__((ext_vector_type(4))) unsigned int u32x4;
typedef __attribute__((ext_vector_type(4))) _Float16 half4;

static __device__ __forceinline__ unsigned short f2bf(float f) {
    __hip_bfloat16 h = __float2bfloat16(f);
    return *reinterpret_cast<unsigned short*>(&h);
}

// async global->LDS, 16B per lane; LDS dest = base + lane*16 (wave-uniform base)
static __device__ __forceinline__ void gload16(const void* g, void* l) {
    __builtin_amdgcn_global_load_lds(
        (const __attribute__((address_space(1))) void*)(g),
        (__attribute__((address_space(3))) void*)(l), 16, 0, 0);
}

__device__ __forceinline__ void storeC_helper(float* C, size_t idx, float v) { C[idx] = v; }
__device__ __forceinline__ void storeC_helper(__hip_bfloat16* C, size_t idx, float v) { C[idx] = __float2bfloat16(v); }

// ---- scheduling primitives for the 8-phase GEMM (raw barriers, counted waits) ----
#define GFENCE()  asm volatile("" ::: "memory")
#define GBAR()    do { GFENCE(); __builtin_amdgcn_s_barrier(); GFENCE(); } while (0)
// rule #18: sched_barrier(0) after inline-asm lgkmcnt so MFMAs can't hoist above it
#define GWAITL0() do { asm volatile("s_waitcnt lgkmcnt(0)" ::: "memory"); __builtin_amdgcn_sched_barrier(0); } while (0)
#define GWAITV(n) asm volatile("s_waitcnt vmcnt(" n ")" ::: "memory")

// ---------------- fused cast fp32 -> bf16 (x + 4 weights, one launch) ----------------
__global__ __launch_bounds__(256) void cast_all(const float* __restrict__ x,
                                                const float* __restrict__ wq,
                                                const float* __restrict__ wk,
                                                const float* __restrict__ wv,
                                                const float* __restrict__ wo,
                                                __hip_bfloat16* __restrict__ xb,
                                                __hip_bfloat16* __restrict__ wqkvb,
                                                __hip_bfloat16* __restrict__ wob) {
    const int VX = (BATCH * SEQ * DIM) / 4;
    const int VW = (DIM * DIM) / 4;
    int v = blockIdx.x * blockDim.x + threadIdx.x;
    const float* src; __hip_bfloat16* dst; int off;
    if (v < VX)               { src = x;  dst = xb;                            off = v; }
    else if (v < VX + VW)     { src = wq; dst = wqkvb;                         off = v - VX; }
    else if (v < VX + 2 * VW) { src = wk; dst = wqkvb + (size_t)DIM * DIM;     off = v - VX - VW; }
    else if (v < VX + 3 * VW) { src = wv; dst = wqkvb + 2ull * DIM * DIM;      off = v - VX - 2 * VW; }
    else                      { src = wo; dst = wob;                           off = v - VX - 3 * VW; }
    float4 f = *(const float4*)(src + (size_t)off * 4);
    union { unsigned short u[4]; uint2 d; } pk;
    pk.u[0] = f2bf(f.x); pk.u[1] = f2bf(f.y); pk.u[2] = f2bf(f.z); pk.u[3] = f2bf(f.w);
    *(uint2*)(dst + (size_t)off * 4) = pk.d;
}

// ---------------- 256x256 8-phase bf16 GEMM (QKV, fused RoPE + V-transpose) ----------
// C[m,n] = sum_k A[m,k]*B[n,k], M=4096, N=6144, K=2048.
// 512 thr = 8 waves (2M x 4N); per-wave out 128x64 (acc[8][4]); BK=64; LDS 128KB.
// Schedule: per iteration 2 K-tiles, 8 phases. Tile frags front-loaded in p1/p2
// (12+12 ds_read_b128) so the buffer is free from p3 on; 1 half-tile (2 gload16)
// staged per phase (p7 stages 2, p2 none); counted vmcnt(4)@p4 / vmcnt(6)@p8,
// never 0 in the main loop. setprio(1) wraps each 16-MFMA cluster.
template <int MOFF>
static __device__ __forceinline__ void mfma16(const short8* af, const short8* bf,
                                              f32x4 (&acc)[8][4]) {
    __builtin_amdgcn_s_setprio(1);
#pragma unroll
    for (int mt = 0; mt < 4; mt++)
#pragma unroll
        for (int nt = 0; nt < 4; nt++)
            acc[MOFF + mt][nt] = __builtin_amdgcn_mfma_f32_16x16x32_bf16(
                af[MOFF + mt], bf[nt], acc[MOFF + mt][nt], 0, 0, 0);
    __builtin_amdgcn_s_setprio(0);
}

__global__ __launch_bounds__(512, 2) void gemm256_qkv(const __hip_bfloat16* __restrict__ A,
                                                      const __hip_bfloat16* __restrict__ B,
                                                      __hip_bfloat16* __restrict__ C,
                                                      _Float16* __restrict__ vt) {
    constexpr int K  = DIM;       // 2048
    constexpr int N  = QKVN;      // 6144
    constexpr int NT = K / 64;    // 32 K-tiles
    constexpr int NI = NT / 2;    // 16 iterations
    __shared__ __align__(16) __hip_bfloat16 As[2][256 * 64];   // 64KB
    __shared__ __align__(16) __hip_bfloat16 Bs[2][256 * 64];   // 64KB

    int tid  = threadIdx.x;
    int lane = tid & 63;
    int wave = tid >> 6;
    int wm   = wave >> 2;      // 0..1  (M half)
    int wn   = wave & 3;       // 0..3  (N quarter)
    int quad = lane >> 4;
    int l15  = lane & 15;
    int m0   = blockIdx.y * 256;
    int n0   = blockIdx.x * 256;

    f32x4 acc[8][4] = {};

    // half-tile stage: h=0,1 -> A rows h*128.., h=2,3 -> B rows (h-2)*128..
    // LDS linear dest; source chunk pre-swizzled so reads use phys = c ^ (row&7).
    auto stage = [&](int tau, int h) {
        const __hip_bfloat16* src;
        __hip_bfloat16* dst;
        if (h < 2) { src = A + (size_t)(m0 + h * 128) * K + tau * 64;
                     dst = &As[tau & 1][h * 8192]; }
        else       { src = B + (size_t)(n0 + (h - 2) * 128) * K + tau * 64;
                     dst = &Bs[tau & 1][(h - 2) * 8192]; }
#pragma unroll
        for (int c = 0; c < 2; c++) {
            int br = (wave * 2 + c) * 8;
            int r  = br + (lane >> 3);
            int cc = (lane & 7) ^ (r & 7);
            gload16(src + (size_t)r * K + cc * 8, dst + br * 64);
        }
    };

    // per-thread constant fragment bases (row&7 == l15&7 for all mt/nt)
    int swz = l15 & 7;
    const __hip_bfloat16* a00 = &As[0][(wm * 128 + l15) * 64 + ((quad    ) ^ swz) * 8]; // kk0
    const __hip_bfloat16* a01 = &As[0][(wm * 128 + l15) * 64 + ((4 + quad) ^ swz) * 8]; // kk1
    const __hip_bfloat16* b00 = &Bs[0][(wn * 64  + l15) * 64 + ((quad    ) ^ swz) * 8];
    const __hip_bfloat16* b01 = &Bs[0][(wn * 64  + l15) * 64 + ((4 + quad) ^ swz) * 8];

    short8 a0[8], a1[8], b0[4], b1[4];

    // ---- prologue: tile0 fully + tile1 h0..h2; complete tile0, keep 3 halves in flight
    stage(0, 0); stage(0, 1); stage(0, 2); stage(0, 3);
    stage(1, 0); stage(1, 1); stage(1, 2);
    GWAITV("6");
    GBAR();

#pragma unroll 1
    for (int i = 0; i < NI; i++) {
        const bool nl = (i < NI - 1);
        // ---- p1: tile t (buf0) kk0+kk1... kk0 reads + stage (t+1)h3
#pragma unroll
        for (int mt = 0; mt < 8; mt++) a0[mt] = *(const short8*)(a00 + mt * 1024);
#pragma unroll
        for (int nt = 0; nt < 4; nt++) b0[nt] = *(const short8*)(b00 + nt * 1024);
        stage(2 * i + 1, 3);
        GBAR(); GWAITL0(); mfma16<0>(a0, b0, acc); GBAR();
        // ---- p2: kk1 reads (buf0 fully register-resident after this phase)
#pragma unroll
        for (int mt = 0; mt < 8; mt++) a1[mt] = *(const short8*)(a01 + mt * 1024);
#pragma unroll
        for (int nt = 0; nt < 4; nt++) b1[nt] = *(const short8*)(b01 + nt * 1024);
        GBAR(); GWAITL0(); mfma16<4>(a0, b0, acc); GBAR();
        // ---- p3: buf0 now free -> stage (t+2)h0
        if (nl) stage(2 * i + 2, 0);
        GBAR(); GWAITL0(); mfma16<0>(a1, b1, acc); GBAR();
        // ---- p4: stage (t+2)h1; gate tile t+1 complete (vmcnt 4), never 0 mid-loop
        if (nl) stage(2 * i + 2, 1);
        GBAR(); GWAITL0(); mfma16<4>(a1, b1, acc);
        if (nl) { GWAITV("4"); } else { GWAITV("0"); }
        GBAR();
        // ---- p5: tile t+1 (buf1) kk0 reads + stage (t+2)h2
#pragma unroll
        for (int mt = 0; mt < 8; mt++) a0[mt] = *(const short8*)(a00 + 16384 + mt * 1024);
#pragma unroll
        for (int nt = 0; nt < 4; nt++) b0[nt] = *(const short8*)(b00 + 16384 + nt * 1024);
        if (nl) stage(2 * i + 2, 2);
        GBAR(); GWAITL0(); mfma16<0>(a0, b0, acc); GBAR();
        // ---- p6: kk1 reads + stage (t+2)h3 (buf1 register-resident after this phase)
#pragma unroll
        for (int mt = 0; mt < 8; mt++) a1[mt] = *(const short8*)(a01 + 16384 + mt * 1024);
#pragma unroll
        for (int nt = 0; nt < 4; nt++) b1[nt] = *(const short8*)(b01 + 16384 + nt * 1024);
        if (nl) stage(2 * i + 2, 3);
        GBAR(); GWAITL0(); mfma16<4>(a0, b0, acc); GBAR();
        // ---- p7: buf1 free -> stage (t+3)h0,h1 (double slot)
        if (nl) { stage(2 * i + 3, 0); stage(2 * i + 3, 1); }
        GBAR(); GWAITL0(); mfma16<0>(a1, b1, acc); GBAR();
        // ---- p8: stage (t+3)h2; gate tile t+2 complete (vmcnt 6 -> 3 halves in flight)
        if (nl) stage(2 * i + 3, 2);
        GBAR(); GWAITL0(); mfma16<4>(a1, b1, acc);
        if (nl) GWAITV("6");
        GBAR();
    }

    // ---------------- epilogue (block-uniform branch: n0 aligned to 256) ----------------
    int ncol0 = n0 + wn * 64;
    if (ncol0 >= 4096) {
        // V: transpose per-wave 128(s) x 64(d) via private 16KB LDS region, store f16
        _Float16* T = ((wave < 4) ? (_Float16*)As : (_Float16*)Bs) + (wave & 3) * 8192;
#pragma unroll
        for (int mt = 0; mt < 8; mt++)
#pragma unroll
            for (int nt = 0; nt < 4; nt++) {
                half4 hv;
#pragma unroll
                for (int r = 0; r < 4; r++) hv[r] = (_Float16)acc[mt][nt][r];
                int chunk = mt * 2 + (quad >> 1);       // s>>3
                int phys  = chunk ^ l15;                // ^ (d&15), d = nt*16+l15
                *(half4*)(T + (nt * 16 + l15) * 128 + phys * 8 + (quad & 1) * 4) = hv;
            }
        int h  = (ncol0 - 4096) >> 7;
        int d0 = (ncol0 - 4096) & 127;                  // 0 or 64
        int b  = (m0 + wm * 128) >> 11;
        int sb = (m0 + wm * 128) & (SEQ - 1);
#pragma unroll
        for (int pass = 0; pass < 16; pass++) {
            int d = pass * 4 + quad;
            int phys = l15 ^ (d & 15);
            u32x4 val = *(const u32x4*)(T + d * 128 + phys * 8);
            *(u32x4*)(vt + ((size_t)((b * NH + h) * HD + d0 + d)) * SEQ + sb + l15 * 8) = val;
        }
    } else {
        // Q,K: fused RoPE + bf16 store
#pragma unroll
        for (int nt = 0; nt < 4; nt++) {
            int col = ncol0 + nt * 16 + l15;
            float theta = __expf(-((float)((col & 127) & ~1) * (1.0f / (float)HD)) * 9.210340371976184f);
#pragma unroll
            for (int mt = 0; mt < 8; mt++)
#pragma unroll
                for (int r = 0; r < 4; r++) {
                    int row = m0 + wm * 128 + mt * 16 + quad * 4 + r;
                    float val = acc[mt][nt][r];
                    float part = __shfl_xor(val, 1);
                    int s = row & (SEQ - 1);
                    float sn, cs;
                    __sincosf((float)s * theta, &sn, &cs);
                    val = (l15 & 1) ? val * cs + part * sn : val * cs - part * sn;
                    C[(size_t)row * N + col] = __float2bfloat16(val);
                }
        }
    }
}

// ---------------- bf16 GEMM, C[m,n] = sum_k A[m,k]*B[n,k] (128x128, out-proj) --------
template <int MODE, typename OutT>
__global__ __launch_bounds__(256) void gemm_bt(const __hip_bfloat16* __restrict__ A,
                                               const __hip_bfloat16* __restrict__ B,
                                               OutT* __restrict__ C,
                                               _Float16* __restrict__ vt,
                                               int M, int N, int K) {
    constexpr int BK = 64;
    __shared__ __align__(16) __hip_bfloat16 As[128 * BK];
    __shared__ __align__(16) __hip_bfloat16 Bs[128 * BK];
    int tid  = threadIdx.x;
    int lane = tid & 63;
    int wave = tid >> 6;
    int quad = lane >> 4;
    int l15  = lane & 15;
    int wr   = wave >> 1, wc = wave & 1;
    int m0 = blockIdx.y * 128;
    int n0 = blockIdx.x * 128;
    f32x4 acc[4][4] = {};

    for (int k0 = 0; k0 < K; k0 += BK) {
        __syncthreads();
#pragma unroll
        for (int c = 0; c < 4; c++) {
            int br = (wave * 4 + c) * 8;
            int r  = br + (lane >> 3);
            int cc = (lane & 7) ^ (r & 7);
            gload16(A + (size_t)(m0 + r) * K + k0 + cc * 8, As + br * 64);
            gload16(B + (size_t)(n0 + r) * K + k0 + cc * 8, Bs + br * 64);
        }
        __syncthreads();
#pragma unroll
        for (int kk = 0; kk < BK; kk += 32) {
            short8 af[4], bf4[4];
#pragma unroll
            for (int t = 0; t < 4; t++) {
                int Ra = wr * 64 + t * 16 + l15;
                int pa = ((kk >> 3) + quad) ^ (Ra & 7);
                af[t] = *(const short8*)(As + Ra * 64 + pa * 8);
                int Rb = wc * 64 + t * 16 + l15;
                int pb = ((kk >> 3) + quad) ^ (Rb & 7);
                bf4[t] = *(const short8*)(Bs + Rb * 64 + pb * 8);
            }
#pragma unroll
            for (int mt = 0; mt < 4; mt++)
#pragma unroll
                for (int nt = 0; nt < 4; nt++)
                    acc[mt][nt] = __builtin_amdgcn_mfma_f32_16x16x32_bf16(af[mt], bf4[nt], acc[mt][nt], 0, 0, 0);
        }
    }

#pragma unroll
    for (int nt = 0; nt < 4; nt++) {
        int col = n0 + wc * 64 + nt * 16 + l15;
#pragma unroll
        for (int mt = 0; mt < 4; mt++)
#pragma unroll
            for (int r = 0; r < 4; r++) {
                int row = m0 + wr * 64 + mt * 16 + quad * 4 + r;
                storeC_helper(C, (size_t)row * N + col, acc[mt][nt][r]);
            }
    }
}

// ---------------- flash attention (causal) ----------------
// 512 threads = 8 waves = 2 groups x 4. qtile=128 (wave owns 32 q-rows).
// Group g processes half the key range; online-softmax partials merged in LDS.
// Pairs (i,15-i): every block 17+17 iters. grid (8,32)=256 blocks, 2 waves/SIMD.
// S^T = K·Q^T so P exits in B-operand layout for 16x16x16 f16 PV.
__global__ __launch_bounds__(512, 2) void flash_kernel(const __hip_bfloat16* __restrict__ qkv,
                                                       const _Float16* __restrict__ vt,
                                                       __hip_bfloat16* __restrict__ attn) {
    __shared__ __align__(16) __hip_bfloat16 Ks[2][2][64 * 128];   // [group][buf] 64KB
    __shared__ __align__(16) _Float16 Vts[2][2][128 * 64];        // [group][buf] 64KB
    int tid  = threadIdx.x;
    int lane = tid & 63;
    int wave = tid >> 6;
    int grp  = wave >> 2;
    int wl   = wave & 3;
    int quad = lane >> 4;
    int l15  = lane & 15;
    int pairi = blockIdx.x;
    int bh = blockIdx.y;
    int b  = bh >> 4;
    int h  = bh & 15;
    size_t row0 = (size_t)b * SEQ;
    const _Float16* vbase = vt + (size_t)bh * HD * SEQ;
    const float scale = 0.08838834764831845f;
    const float NEG = -1e30f;

    auto stage = [&](int buf, int kt) {
#pragma unroll
        for (int c = 0; c < 4; c++) {
            int br = (wl * 4 + c) * 4;
            int r  = br + (lane >> 4);
            int cc = (lane & 15) ^ (r & 15);
            gload16(qkv + (row0 + kt * 64 + r) * (size_t)QKVN + DIM + h * HD + cc * 8,
                    &Ks[grp][buf][br * 128]);
        }
#pragma unroll
        for (int c = 0; c < 4; c++) {
            int br = (wl * 4 + c) * 8;
            int r  = br + (lane >> 3);
            int cc = (lane & 7) ^ ((r >> 1) & 7);
            gload16(vbase + (size_t)r * SEQ + kt * 64 + cc * 8, &Vts[grp][buf][br * 64]);
        }
    };

    for (int seg = 0; seg < 2; seg++) {
        int qt = seg ? (15 - pairi) : pairi;
        int half = qt + 1;
        int kbase = grp ? half : 0;

        short8 qf[2][4];
#pragma unroll
        for (int mt = 0; mt < 2; mt++) {
            int qrow = qt * 128 + wl * 32 + mt * 16 + l15;
            const __hip_bfloat16* qptr = qkv + (row0 + qrow) * (size_t)QKVN + h * HD + quad * 8;
#pragma unroll
            for (int c = 0; c < 4; c++) qf[mt][c] = *(const short8*)(qptr + c * 32);
        }
        f32x4 o[2][8] = {};
        float m_[2] = {NEG, NEG}, l_[2] = {0.f, 0.f};

        stage(0, kbase);

        for (int i = 0; i < half; i++) {
            __syncthreads();
            if (i + 1 < half) stage((i + 1) & 1, kbase + i + 1);
            int kt = kbase + i;
            const __hip_bfloat16* ks = Ks[grp][i & 1];
            const _Float16* vts = Vts[grp][i & 1];

            f32x4 s[2][4] = {};
#pragma unroll
            for (int ktile = 0; ktile < 4; ktile++) {
                int R = ktile * 16 + l15;
#pragma unroll
                for (int c = 0; c < 4; c++) {
                    int phys = (c * 4 + quad) ^ (R & 15);
                    short8 kf = *(const short8*)(ks + R * 128 + phys * 8);
                    s[0][ktile] = __builtin_amdgcn_mfma_f32_16x16x32_bf16(kf, qf[0][c], s[0][ktile], 0, 0, 0);
                    s[1][ktile] = __builtin_amdgcn_mfma_f32_16x16x32_bf16(kf, qf[1][c], s[1][ktile], 0, 0, 0);
                }
            }
            bool diag = (kt >= 2 * qt);
            float alpha[2];
#pragma unroll
            for (int mt = 0; mt < 2; mt++) {
                int q = qt * 128 + wl * 32 + mt * 16 + l15;
#pragma unroll
                for (int ktile = 0; ktile < 4; ktile++)
#pragma unroll
                    for (int r = 0; r < 4; r++) {
                        float v = s[mt][ktile][r] * scale;
                        if (diag) {
                            int key = kt * 64 + ktile * 16 + quad * 4 + r;
                            if (key > q) v = NEG;
                        }
                        s[mt][ktile][r] = v;
                    }
                float v = s[mt][0][0];
#pragma unroll
                for (int ktile = 0; ktile < 4; ktile++)
#pragma unroll
                    for (int r = 0; r < 4; r++) v = fmaxf(v, s[mt][ktile][r]);
                v = fmaxf(v, __shfl_xor(v, 16));
                v = fmaxf(v, __shfl_xor(v, 32));
                float mnew = fmaxf(m_[mt], v);
                alpha[mt] = __expf(m_[mt] - mnew);
                m_[mt] = mnew;
                float sum = 0.f;
#pragma unroll
                for (int ktile = 0; ktile < 4; ktile++)
#pragma unroll
                    for (int r = 0; r < 4; r++) {
                        float p = __expf(s[mt][ktile][r] - mnew);
                        s[mt][ktile][r] = p;
                        sum += p;
                    }
                sum += __shfl_xor(sum, 16);
                sum += __shfl_xor(sum, 32);
                l_[mt] = l_[mt] * alpha[mt] + sum;
#pragma unroll
                for (int dt = 0; dt < 8; dt++) o[mt][dt] *= alpha[mt];
            }
            half4 pk[2][4];
#pragma unroll
            for (int mt = 0; mt < 2; mt++)
#pragma unroll
                for (int kc = 0; kc < 4; kc++)
#pragma unroll
                    for (int r = 0; r < 4; r++) pk[mt][kc][r] = (_Float16)s[mt][kc][r];
#pragma unroll
            for (int kc = 0; kc < 4; kc++)
#pragma unroll
                for (int dt = 0; dt < 8; dt++) {
                    int d = dt * 16 + l15;
                    int c4 = ((kc * 4 + quad) ^ (d & 14));
                    half4 vf = *(const half4*)(vts + d * 64 + c4 * 4);
                    o[0][dt] = __builtin_amdgcn_mfma_f32_16x16x16f16(vf, pk[0][kc], o[0][dt], 0, 0, 0);
                    o[1][dt] = __builtin_amdgcn_mfma_f32_16x16x16f16(vf, pk[1][kc], o[1][dt], 0, 0, 0);
                }
        }

        __syncthreads();
        float* o1mb = (float*)&Ks[0][0][0];
        float* mlmb = (float*)&Vts[0][0][0];
        __hip_bfloat16* tb = (__hip_bfloat16*)((char*)&Vts[0][0][0] + 8192);
        if (grp == 1) {
            float* dst = o1mb + wl * 4096;
#pragma unroll
            for (int mt = 0; mt < 2; mt++)
#pragma unroll
                for (int dt = 0; dt < 8; dt++)
#pragma unroll
                    for (int r = 0; r < 4; r++)
                        dst[((mt * 8 + dt) * 4 + r) * 64 + lane] = o[mt][dt][r];
            float* ml = mlmb + (wl * 64 + lane) * 4;
            ml[0] = m_[0]; ml[1] = m_[1]; ml[2] = l_[0]; ml[3] = l_[1];
        }
        __syncthreads();
        if (grp == 0) {
            const float* src = o1mb + wl * 4096;
            const float* ml = mlmb + (wl * 64 + lane) * 4;
#pragma unroll
            for (int mt = 0; mt < 2; mt++) {
                float m1 = ml[mt], l1 = ml[2 + mt];
                float mm = fmaxf(m_[mt], m1);
                float a0 = __expf(m_[mt] - mm), a1 = __expf(m1 - mm);
                float linv = 1.0f / (l_[mt] * a0 + l1 * a1);
#pragma unroll
                for (int dt = 0; dt < 8; dt++)
#pragma unroll
                    for (int r = 0; r < 4; r++)
                        o[mt][dt][r] = (o[mt][dt][r] * a0 +
                                        src[((mt * 8 + dt) * 4 + r) * 64 + lane] * a1) * linv;
            }
            __hip_bfloat16* tw = tb + wl * 4096;
#pragma unroll
            for (int mt = 0; mt < 2; mt++)
#pragma unroll
                for (int dt = 0; dt < 8; dt++) {
                    int q32 = mt * 16 + l15;
                    int c4 = dt * 4 + quad;
                    int phys = c4 ^ ((q32 & 7) << 2);
                    union { unsigned short u[4]; uint2 dw; } pkb;
#pragma unroll
                    for (int r = 0; r < 4; r++) pkb.u[r] = f2bf(o[mt][dt][r]);
                    *(uint2*)(tw + q32 * 128 + phys * 4) = pkb.dw;
                }
#pragma unroll
            for (int pass = 0; pass < 8; pass++) {
                int q32 = pass * 4 + (lane >> 4);
                int p = l15;
                int phys = (p * 2) ^ ((q32 & 7) << 2);
                u32x4 val = *(const u32x4*)(tw + q32 * 128 + phys * 4);
                int qg = qt * 128 + wl * 32 + q32;
                *(u32x4*)(attn + (row0 + qg) * (size_t)DIM + h * HD + p * 8) = val;
            }
        }
        __syncthreads();
    }
}

extern "C" void kernel_launch(void* const* d_in, const int* in_sizes, int n_in,
                              void* d_out, int out_size, void* d_ws, size_t ws_size,
                              hipStream_t stream) {
    const float* x  = (const float*)d_in[0];
    const float* wq = (const float*)d_in[2];
    const float* wk = (const float*)d_in[3];
    const float* wv = (const float*)d_in[4];
    const float* wo = (const float*)d_in[5];
    float* out = (float*)d_out;

    char* ws = (char*)d_ws;
    __hip_bfloat16* xb    = (__hip_bfloat16*)(ws);                 // 4096x2048 (16MB)
    __hip_bfloat16* attn  = (__hip_bfloat16*)(ws);                 // reuses xb after QKV GEMM
    __hip_bfloat16* wqkvb = (__hip_bfloat16*)(ws + 16777216ull);   // 6144x2048 (24MB)
    __hip_bfloat16* wob   = (__hip_bfloat16*)(ws + 41943040ull);   // 2048x2048 (8MB)
    __hip_bfloat16* qkv   = (__hip_bfloat16*)(ws + 50331648ull);   // 4096x6144 (48MB; V cols unused)
    _Float16*       vtg   = (_Float16*)(ws + 100663296ull);        // 32x128x2048 f16 (16MB)

    const int nv = (BATCH * SEQ * DIM + 4 * DIM * DIM) / 4;
    cast_all<<<nv / 256, 256, 0, stream>>>(x, wq, wk, wv, wo, xb, wqkvb, wob);

    // QKV = xb @ wqkvb^T, 256x256 8-phase kernel, fused RoPE (Q,K) + V-transpose
    gemm256_qkv<<<dim3(QKVN / 256, (BATCH * SEQ) / 256), 512, 0, stream>>>(
        xb, wqkvb, qkv, vtg);

    flash_kernel<<<dim3(8, BATCH * NH), 512, 0, stream>>>(qkv, vtg, attn);

    // out = attn @ wo^T : M=4096, N=2048, K=2048 (fp32 out)
    gemm_bt<0, float><<<dim3(DIM / 128, (BATCH * SEQ) / 128), 256, 0, stream>>>(
        attn, wob, out, nullptr, BATCH * SEQ, DIM, DIM);
}

// Round 3
// 463.820 us; speedup vs baseline: 1.0004x; 1.0004x over previous
//
#include <hip/hip_runtime.h>
#include <hip/hip_bf16.h>
#include <math.h>

#define DIM   2048
#define NH    16
#define HD    128
#define SEQ   2048
#define BATCH 2
#define QKVN  6144   // 3*DIM

typedef __attribute__((ext_vector_type(8))) short short8;
typedef __attribute__((ext_vector_type(4))) float f32x4;
typedef __attribute__((ext_vector_type(4))) unsigned int u32x4;
typedef __attribute__((ext_vector_type(4))) _Float16 half4;

static __device__ __forceinline__ unsigned short f2bf(float f) {
    __hip_bfloat16 h = __float2bfloat16(f);
    return *reinterpret_cast<unsigned short*>(&h);
}

// async global->LDS, 16B per lane; LDS dest = base + lane*16 (wave-uniform base)
static __device__ __forceinline__ void gload16(const void* g, void* l) {
    __builtin_amdgcn_global_load_lds(
        (const __attribute__((address_space(1))) void*)(g),
        (__attribute__((address_space(3))) void*)(l), 16, 0, 0);
}

__device__ __forceinline__ void storeC_helper(float* C, size_t idx, float v) { C[idx] = v; }
__device__ __forceinline__ void storeC_helper(__hip_bfloat16* C, size_t idx, float v) { C[idx] = __float2bfloat16(v); }

// ---- scheduling primitives for the 8-phase GEMM (raw barriers, counted waits) ----
#define GFENCE()  asm volatile("" ::: "memory")
#define GBAR()    do { GFENCE(); __builtin_amdgcn_s_barrier(); GFENCE(); } while (0)
// rule #18: sched_barrier(0) after inline-asm lgkmcnt so MFMAs can't hoist above it
#define GWAITL0() do { asm volatile("s_waitcnt lgkmcnt(0)" ::: "memory"); __builtin_amdgcn_sched_barrier(0); } while (0)
#define GWAITV(n) asm volatile("s_waitcnt vmcnt(" n ")" ::: "memory")

// ---------------- fused cast fp32 -> bf16 (x + 4 weights, one launch) ----------------
__global__ __launch_bounds__(256) void cast_all(const float* __restrict__ x,
                                                const float* __restrict__ wq,
                                                const float* __restrict__ wk,
                                                const float* __restrict__ wv,
                                                const float* __restrict__ wo,
                                                __hip_bfloat16* __restrict__ xb,
                                                __hip_bfloat16* __restrict__ wqkvb,
                                                __hip_bfloat16* __restrict__ wob) {
    const int VX = (BATCH * SEQ * DIM) / 4;
    const int VW = (DIM * DIM) / 4;
    int v = blockIdx.x * blockDim.x + threadIdx.x;
    const float* src; __hip_bfloat16* dst; int off;
    if (v < VX)               { src = x;  dst = xb;                            off = v; }
    else if (v < VX + VW)     { src = wq; dst = wqkvb;                         off = v - VX; }
    else if (v < VX + 2 * VW) { src = wk; dst = wqkvb + (size_t)DIM * DIM;     off = v - VX - VW; }
    else if (v < VX + 3 * VW) { src = wv; dst = wqkvb + 2ull * DIM * DIM;      off = v - VX - 2 * VW; }
    else                      { src = wo; dst = wob;                           off = v - VX - 3 * VW; }
    float4 f = *(const float4*)(src + (size_t)off * 4);
    union { unsigned short u[4]; uint2 d; } pk;
    pk.u[0] = f2bf(f.x); pk.u[1] = f2bf(f.y); pk.u[2] = f2bf(f.z); pk.u[3] = f2bf(f.w);
    *(uint2*)(dst + (size_t)off * 4) = pk.d;
}

// ---------------- 256x256 8-phase bf16 GEMM (QKV, fused RoPE + V-transpose) ----------
// C[m,n] = sum_k A[m,k]*B[n,k], M=4096, N=6144, K=2048.
// 512 thr = 8 waves (2M x 4N); per-wave out 128x64 (acc[8][4] = 128 VGPR); BK=64.
// Register plan (fix for r2 spill: demand ~233 <= 256-cap via waves_per_eu(2,2)):
//   p1 reads b_kk0 + A[Q0,kk0] + A[Q1,kk0] (12 b128), MFMA Q0xkk0
//   p2 reads b_kk1 + A[Q0,kk1] + A[Q1,kk1] (12 b128), MFMA Q1xkk0
//   p3/p4: no reads, MFMA Q0xkk1 / Q1xkk1  -> buffer free from p3 (stage window)
// Stage: 1 half-tile (2 gload16)/phase (p7 double, p2 none); counted vmcnt(4)@p4,
// vmcnt(6)@p8 -- never 0 in the main loop. setprio(1) wraps each 16-MFMA cluster.
template <int MOFF>
static __device__ __forceinline__ void mfma16(const short8 (&af)[4], const short8 (&bf)[4],
                                              f32x4 (&acc)[8][4]) {
    __builtin_amdgcn_s_setprio(1);
#pragma unroll
    for (int mt = 0; mt < 4; mt++)
#pragma unroll
        for (int nt = 0; nt < 4; nt++)
            acc[MOFF + mt][nt] = __builtin_amdgcn_mfma_f32_16x16x32_bf16(
                af[mt], bf[nt], acc[MOFF + mt][nt], 0, 0, 0);
    __builtin_amdgcn_s_setprio(0);
}

__global__ __attribute__((amdgpu_waves_per_eu(2, 2))) __launch_bounds__(512)
void gemm256_qkv(const __hip_bfloat16* __restrict__ A,
                 const __hip_bfloat16* __restrict__ B,
                 __hip_bfloat16* __restrict__ C,
                 _Float16* __restrict__ vt) {
    constexpr int K  = DIM;       // 2048
    constexpr int N  = QKVN;      // 6144
    constexpr int NT = K / 64;    // 32 K-tiles
    constexpr int NI = NT / 2;    // 16 iterations
    __shared__ __align__(16) __hip_bfloat16 As[2][256 * 64];   // 64KB
    __shared__ __align__(16) __hip_bfloat16 Bs[2][256 * 64];   // 64KB

    int tid  = threadIdx.x;
    int lane = tid & 63;
    int wave = tid >> 6;
    int wm   = wave >> 2;      // 0..1  (M half)
    int wn   = wave & 3;       // 0..3  (N quarter)
    int quad = lane >> 4;
    int l15  = lane & 15;
    int m0   = blockIdx.y * 256;
    int n0   = blockIdx.x * 256;

    f32x4 acc[8][4] = {};

    // half-tile stage: h=0,1 -> A rows h*128.., h=2,3 -> B rows (h-2)*128..
    // LDS linear dest; source chunk pre-swizzled so reads use phys = c ^ (row&7).
    auto stage = [&](int tau, int h) {
        const __hip_bfloat16* src;
        __hip_bfloat16* dst;
        if (h < 2) { src = A + (size_t)(m0 + h * 128) * K + tau * 64;
                     dst = &As[tau & 1][h * 8192]; }
        else       { src = B + (size_t)(n0 + (h - 2) * 128) * K + tau * 64;
                     dst = &Bs[tau & 1][(h - 2) * 8192]; }
#pragma unroll
        for (int c = 0; c < 2; c++) {
            int br = (wave * 2 + c) * 8;
            int r  = br + (lane >> 3);
            int cc = (lane & 7) ^ (r & 7);
            gload16(src + (size_t)r * K + cc * 8, dst + br * 64);
        }
    };

    // per-thread constant fragment bases (row&7 == l15&7 for all mt/nt)
    int swz = l15 & 7;
    const __hip_bfloat16* a00 = &As[0][(wm * 128 + l15) * 64 + ((quad    ) ^ swz) * 8]; // kk0
    const __hip_bfloat16* a01 = &As[0][(wm * 128 + l15) * 64 + ((4 + quad) ^ swz) * 8]; // kk1
    const __hip_bfloat16* b00 = &Bs[0][(wn * 64  + l15) * 64 + ((quad    ) ^ swz) * 8];
    const __hip_bfloat16* b01 = &Bs[0][(wn * 64  + l15) * 64 + ((4 + quad) ^ swz) * 8];

    short8 aA[4], aB[4], aC[4], aD[4], bb0[4], bb1[4];

    // ---- prologue: tile0 fully + tile1 h0..h2; complete tile0, keep 3 halves in flight
    stage(0, 0); stage(0, 1); stage(0, 2); stage(0, 3);
    stage(1, 0); stage(1, 1); stage(1, 2);
    GWAITV("6");
    GBAR();

#pragma unroll 1
    for (int i = 0; i < NI; i++) {
        const bool nl = (i < NI - 1);
        // ================= tile t = 2i (buf0) =================
        // p1: read bb0(kk0), aA=Q0kk0, aB=Q1kk0; stage (t+1)h3; MFMA Q0 x kk0
#pragma unroll
        for (int t = 0; t < 4; t++) aA[t] = *(const short8*)(a00 + t * 1024);
#pragma unroll
        for (int t = 0; t < 4; t++) aB[t] = *(const short8*)(a00 + (4 + t) * 1024);
#pragma unroll
        for (int t = 0; t < 4; t++) bb0[t] = *(const short8*)(b00 + t * 1024);
        stage(2 * i + 1, 3);
        GBAR(); GWAITL0(); mfma16<0>(aA, bb0, acc); GBAR();
        // p2: read bb1(kk1), aC=Q0kk1, aD=Q1kk1; MFMA Q1 x kk0 (buf0 reads done after this)
#pragma unroll
        for (int t = 0; t < 4; t++) aC[t] = *(const short8*)(a01 + t * 1024);
#pragma unroll
        for (int t = 0; t < 4; t++) aD[t] = *(const short8*)(a01 + (4 + t) * 1024);
#pragma unroll
        for (int t = 0; t < 4; t++) bb1[t] = *(const short8*)(b01 + t * 1024);
        GBAR(); GWAITL0(); mfma16<4>(aB, bb0, acc); GBAR();
        // p3: buf0 free -> stage (t+2)h0; MFMA Q0 x kk1
        if (nl) stage(2 * i + 2, 0);
        GBAR(); GWAITL0(); mfma16<0>(aC, bb1, acc); GBAR();
        // p4: stage (t+2)h1; MFMA Q1 x kk1; gate tile t+1 complete (vmcnt 4)
        if (nl) stage(2 * i + 2, 1);
        GBAR(); GWAITL0(); mfma16<4>(aD, bb1, acc);
        if (nl) { GWAITV("4"); } else { GWAITV("0"); }
        GBAR();
        // ================= tile t+1 (buf1) =================
        // p5: read bb0, aA, aB (buf1); stage (t+2)h2; MFMA Q0 x kk0
#pragma unroll
        for (int t = 0; t < 4; t++) aA[t] = *(const short8*)(a00 + 16384 + t * 1024);
#pragma unroll
        for (int t = 0; t < 4; t++) aB[t] = *(const short8*)(a00 + 16384 + (4 + t) * 1024);
#pragma unroll
        for (int t = 0; t < 4; t++) bb0[t] = *(const short8*)(b00 + 16384 + t * 1024);
        if (nl) stage(2 * i + 2, 2);
        GBAR(); GWAITL0(); mfma16<0>(aA, bb0, acc); GBAR();
        // p6: read bb1, aC, aD (buf1); stage (t+2)h3; MFMA Q1 x kk0
#pragma unroll
        for (int t = 0; t < 4; t++) aC[t] = *(const short8*)(a01 + 16384 + t * 1024);
#pragma unroll
        for (int t = 0; t < 4; t++) aD[t] = *(const short8*)(a01 + 16384 + (4 + t) * 1024);
#pragma unroll
        for (int t = 0; t < 4; t++) bb1[t] = *(const short8*)(b01 + 16384 + t * 1024);
        if (nl) stage(2 * i + 2, 3);
        GBAR(); GWAITL0(); mfma16<4>(aB, bb0, acc); GBAR();
        // p7: buf1 free -> stage (t+3)h0,h1 (double slot); MFMA Q0 x kk1
        if (nl) { stage(2 * i + 3, 0); stage(2 * i + 3, 1); }
        GBAR(); GWAITL0(); mfma16<0>(aC, bb1, acc); GBAR();
        // p8: stage (t+3)h2; MFMA Q1 x kk1; gate tile t+2 complete (vmcnt 6)
        if (nl) stage(2 * i + 3, 2);
        GBAR(); GWAITL0(); mfma16<4>(aD, bb1, acc);
        if (nl) GWAITV("6");
        GBAR();
    }

    // ---------------- epilogue (block-uniform branch: n0 aligned to 256) ----------------
    int ncol0 = n0 + wn * 64;
    if (ncol0 >= 4096) {
        // V: transpose per-wave 128(s) x 64(d) via private 16KB LDS region, store f16
        _Float16* T = ((wave < 4) ? (_Float16*)As : (_Float16*)Bs) + (wave & 3) * 8192;
#pragma unroll
        for (int mt = 0; mt < 8; mt++)
#pragma unroll
            for (int nt = 0; nt < 4; nt++) {
                half4 hv;
#pragma unroll
                for (int r = 0; r < 4; r++) hv[r] = (_Float16)acc[mt][nt][r];
                int chunk = mt * 2 + (quad >> 1);       // s>>3
                int phys  = chunk ^ l15;                // ^ (d&15), d = nt*16+l15
                *(half4*)(T + (nt * 16 + l15) * 128 + phys * 8 + (quad & 1) * 4) = hv;
            }
        int h  = (ncol0 - 4096) >> 7;
        int d0 = (ncol0 - 4096) & 127;                  // 0 or 64
        int b  = (m0 + wm * 128) >> 11;
        int sb = (m0 + wm * 128) & (SEQ - 1);
#pragma unroll
        for (int pass = 0; pass < 16; pass++) {
            int d = pass * 4 + quad;
            int phys = l15 ^ (d & 15);
            u32x4 val = *(const u32x4*)(T + d * 128 + phys * 8);
            *(u32x4*)(vt + ((size_t)((b * NH + h) * HD + d0 + d)) * SEQ + sb + l15 * 8) = val;
        }
    } else {
        // Q,K: fused RoPE + bf16 store
#pragma unroll
        for (int nt = 0; nt < 4; nt++) {
            int col = ncol0 + nt * 16 + l15;
            float theta = __expf(-((float)((col & 127) & ~1) * (1.0f / (float)HD)) * 9.210340371976184f);
#pragma unroll
            for (int mt = 0; mt < 8; mt++)
#pragma unroll
                for (int r = 0; r < 4; r++) {
                    int row = m0 + wm * 128 + mt * 16 + quad * 4 + r;
                    float val = acc[mt][nt][r];
                    float part = __shfl_xor(val, 1);
                    int s = row & (SEQ - 1);
                    float sn, cs;
                    __sincosf((float)s * theta, &sn, &cs);
                    val = (l15 & 1) ? val * cs + part * sn : val * cs - part * sn;
                    C[(size_t)row * N + col] = __float2bfloat16(val);
                }
        }
    }
}

// ---------------- bf16 GEMM, C[m,n] = sum_k A[m,k]*B[n,k] (128x128, out-proj) --------
template <int MODE, typename OutT>
__global__ __launch_bounds__(256) void gemm_bt(const __hip_bfloat16* __restrict__ A,
                                               const __hip_bfloat16* __restrict__ B,
                                               OutT* __restrict__ C,
                                               _Float16* __restrict__ vt,
                                               int M, int N, int K) {
    constexpr int BK = 64;
    __shared__ __align__(16) __hip_bfloat16 As[128 * BK];
    __shared__ __align__(16) __hip_bfloat16 Bs[128 * BK];
    int tid  = threadIdx.x;
    int lane = tid & 63;
    int wave = tid >> 6;
    int quad = lane >> 4;
    int l15  = lane & 15;
    int wr   = wave >> 1, wc = wave & 1;
    int m0 = blockIdx.y * 128;
    int n0 = blockIdx.x * 128;
    f32x4 acc[4][4] = {};

    for (int k0 = 0; k0 < K; k0 += BK) {
        __syncthreads();
#pragma unroll
        for (int c = 0; c < 4; c++) {
            int br = (wave * 4 + c) * 8;
            int r  = br + (lane >> 3);
            int cc = (lane & 7) ^ (r & 7);
            gload16(A + (size_t)(m0 + r) * K + k0 + cc * 8, As + br * 64);
            gload16(B + (size_t)(n0 + r) * K + k0 + cc * 8, Bs + br * 64);
        }
        __syncthreads();
#pragma unroll
        for (int kk = 0; kk < BK; kk += 32) {
            short8 af[4], bf4[4];
#pragma unroll
            for (int t = 0; t < 4; t++) {
                int Ra = wr * 64 + t * 16 + l15;
                int pa = ((kk >> 3) + quad) ^ (Ra & 7);
                af[t] = *(const short8*)(As + Ra * 64 + pa * 8);
                int Rb = wc * 64 + t * 16 + l15;
                int pb = ((kk >> 3) + quad) ^ (Rb & 7);
                bf4[t] = *(const short8*)(Bs + Rb * 64 + pb * 8);
            }
#pragma unroll
            for (int mt = 0; mt < 4; mt++)
#pragma unroll
                for (int nt = 0; nt < 4; nt++)
                    acc[mt][nt] = __builtin_amdgcn_mfma_f32_16x16x32_bf16(af[mt], bf4[nt], acc[mt][nt], 0, 0, 0);
        }
    }

#pragma unroll
    for (int nt = 0; nt < 4; nt++) {
        int col = n0 + wc * 64 + nt * 16 + l15;
#pragma unroll
        for (int mt = 0; mt < 4; mt++)
#pragma unroll
            for (int r = 0; r < 4; r++) {
                int row = m0 + wr * 64 + mt * 16 + quad * 4 + r;
                storeC_helper(C, (size_t)row * N + col, acc[mt][nt][r]);
            }
    }
}

// ---------------- flash attention (causal) ----------------
// 512 threads = 8 waves = 2 groups x 4. qtile=128 (wave owns 32 q-rows).
// Group g processes half the key range; online-softmax partials merged in LDS.
// Pairs (i,15-i): every block 17+17 iters. grid (8,32)=256 blocks, 2 waves/SIMD.
// S^T = K·Q^T so P exits in B-operand layout for 16x16x16 f16 PV.
__global__ __launch_bounds__(512, 2) void flash_kernel(const __hip_bfloat16* __restrict__ qkv,
                                                       const _Float16* __restrict__ vt,
                                                       __hip_bfloat16* __restrict__ attn) {
    __shared__ __align__(16) __hip_bfloat16 Ks[2][2][64 * 128];   // [group][buf] 64KB
    __shared__ __align__(16) _Float16 Vts[2][2][128 * 64];        // [group][buf] 64KB
    int tid  = threadIdx.x;
    int lane = tid & 63;
    int wave = tid >> 6;
    int grp  = wave >> 2;
    int wl   = wave & 3;
    int quad = lane >> 4;
    int l15  = lane & 15;
    int pairi = blockIdx.x;
    int bh = blockIdx.y;
    int b  = bh >> 4;
    int h  = bh & 15;
    size_t row0 = (size_t)b * SEQ;
    const _Float16* vbase = vt + (size_t)bh * HD * SEQ;
    const float scale = 0.08838834764831845f;
    const float NEG = -1e30f;

    auto stage = [&](int buf, int kt) {
#pragma unroll
        for (int c = 0; c < 4; c++) {
            int br = (wl * 4 + c) * 4;
            int r  = br + (lane >> 4);
            int cc = (lane & 15) ^ (r & 15);
            gload16(qkv + (row0 + kt * 64 + r) * (size_t)QKVN + DIM + h * HD + cc * 8,
                    &Ks[grp][buf][br * 128]);
        }
#pragma unroll
        for (int c = 0; c < 4; c++) {
            int br = (wl * 4 + c) * 8;
            int r  = br + (lane >> 3);
            int cc = (lane & 7) ^ ((r >> 1) & 7);
            gload16(vbase + (size_t)r * SEQ + kt * 64 + cc * 8, &Vts[grp][buf][br * 64]);
        }
    };

    for (int seg = 0; seg < 2; seg++) {
        int qt = seg ? (15 - pairi) : pairi;
        int half = qt + 1;
        int kbase = grp ? half : 0;

        short8 qf[2][4];
#pragma unroll
        for (int mt = 0; mt < 2; mt++) {
            int qrow = qt * 128 + wl * 32 + mt * 16 + l15;
            const __hip_bfloat16* qptr = qkv + (row0 + qrow) * (size_t)QKVN + h * HD + quad * 8;
#pragma unroll
            for (int c = 0; c < 4; c++) qf[mt][c] = *(const short8*)(qptr + c * 32);
        }
        f32x4 o[2][8] = {};
        float m_[2] = {NEG, NEG}, l_[2] = {0.f, 0.f};

        stage(0, kbase);

        for (int i = 0; i < half; i++) {
            __syncthreads();
            if (i + 1 < half) stage((i + 1) & 1, kbase + i + 1);
            int kt = kbase + i;
            const __hip_bfloat16* ks = Ks[grp][i & 1];
            const _Float16* vts = Vts[grp][i & 1];

            f32x4 s[2][4] = {};
#pragma unroll
            for (int ktile = 0; ktile < 4; ktile++) {
                int R = ktile * 16 + l15;
#pragma unroll
                for (int c = 0; c < 4; c++) {
                    int phys = (c * 4 + quad) ^ (R & 15);
                    short8 kf = *(const short8*)(ks + R * 128 + phys * 8);
                    s[0][ktile] = __builtin_amdgcn_mfma_f32_16x16x32_bf16(kf, qf[0][c], s[0][ktile], 0, 0, 0);
                    s[1][ktile] = __builtin_amdgcn_mfma_f32_16x16x32_bf16(kf, qf[1][c], s[1][ktile], 0, 0, 0);
                }
            }
            bool diag = (kt >= 2 * qt);
            float alpha[2];
#pragma unroll
            for (int mt = 0; mt < 2; mt++) {
                int q = qt * 128 + wl * 32 + mt * 16 + l15;
#pragma unroll
                for (int ktile = 0; ktile < 4; ktile++)
#pragma unroll
                    for (int r = 0; r < 4; r++) {
                        float v = s[mt][ktile][r] * scale;
                        if (diag) {
                            int key = kt * 64 + ktile * 16 + quad * 4 + r;
                            if (key > q) v = NEG;
                        }
                        s[mt][ktile][r] = v;
                    }
                float v = s[mt][0][0];
#pragma unroll
                for (int ktile = 0; ktile < 4; ktile++)
#pragma unroll
                    for (int r = 0; r < 4; r++) v = fmaxf(v, s[mt][ktile][r]);
                v = fmaxf(v, __shfl_xor(v, 16));
                v = fmaxf(v, __shfl_xor(v, 32));
                float mnew = fmaxf(m_[mt], v);
                alpha[mt] = __expf(m_[mt] - mnew);
                m_[mt] = mnew;
                float sum = 0.f;
#pragma unroll
                for (int ktile = 0; ktile < 4; ktile++)
#pragma unroll
                    for (int r = 0; r < 4; r++) {
                        float p = __expf(s[mt][ktile][r] - mnew);
                        s[mt][ktile][r] = p;
                        sum += p;
                    }
                sum += __shfl_xor(sum, 16);
                sum += __shfl_xor(sum, 32);
                l_[mt] = l_[mt] * alpha[mt] + sum;
#pragma unroll
                for (int dt = 0; dt < 8; dt++) o[mt][dt] *= alpha[mt];
            }
            half4 pk[2][4];
#pragma unroll
            for (int mt = 0; mt < 2; mt++)
#pragma unroll
                for (int kc = 0; kc < 4; kc++)
#pragma unroll
                    for (int r = 0; r < 4; r++) pk[mt][kc][r] = (_Float16)s[mt][kc][r];
#pragma unroll
            for (int kc = 0; kc < 4; kc++)
#pragma unroll
                for (int dt = 0; dt < 8; dt++) {
                    int d = dt * 16 + l15;
                    int c4 = ((kc * 4 + quad) ^ (d & 14));
                    half4 vf = *(const half4*)(vts + d * 64 + c4 * 4);
                    o[0][dt] = __builtin_amdgcn_mfma_f32_16x16x16f16(vf, pk[0][kc], o[0][dt], 0, 0, 0);
                    o[1][dt] = __builtin_amdgcn_mfma_f32_16x16x16f16(vf, pk[1][kc], o[1][dt], 0, 0, 0);
                }
        }

        __syncthreads();
        float* o1mb = (float*)&Ks[0][0][0];
        float* mlmb = (float*)&Vts[0][0][0];
        __hip_bfloat16* tb = (__hip_bfloat16*)((char*)&Vts[0][0][0] + 8192);
        if (grp == 1) {
            float* dst = o1mb + wl * 4096;
#pragma unroll
            for (int mt = 0; mt < 2; mt++)
#pragma unroll
                for (int dt = 0; dt < 8; dt++)
#pragma unroll
                    for (int r = 0; r < 4; r++)
                        dst[((mt * 8 + dt) * 4 + r) * 64 + lane] = o[mt][dt][r];
            float* ml = mlmb + (wl * 64 + lane) * 4;
            ml[0] = m_[0]; ml[1] = m_[1]; ml[2] = l_[0]; ml[3] = l_[1];
        }
        __syncthreads();
        if (grp == 0) {
            const float* src = o1mb + wl * 4096;
            const float* ml = mlmb + (wl * 64 + lane) * 4;
#pragma unroll
            for (int mt = 0; mt < 2; mt++) {
                float m1 = ml[mt], l1 = ml[2 + mt];
                float mm = fmaxf(m_[mt], m1);
                float a0 = __expf(m_[mt] - mm), a1 = __expf(m1 - mm);
                float linv = 1.0f / (l_[mt] * a0 + l1 * a1);
#pragma unroll
                for (int dt = 0; dt < 8; dt++)
#pragma unroll
                    for (int r = 0; r < 4; r++)
                        o[mt][dt][r] = (o[mt][dt][r] * a0 +
                                        src[((mt * 8 + dt) * 4 + r) * 64 + lane] * a1) * linv;
            }
            __hip_bfloat16* tw = tb + wl * 4096;
#pragma unroll
            for (int mt = 0; mt < 2; mt++)
#pragma unroll
                for (int dt = 0; dt < 8; dt++) {
                    int q32 = mt * 16 + l15;
                    int c4 = dt * 4 + quad;
                    int phys = c4 ^ ((q32 & 7) << 2);
                    union { unsigned short u[4]; uint2 dw; } pkb;
#pragma unroll
                    for (int r = 0; r < 4; r++) pkb.u[r] = f2bf(o[mt][dt][r]);
                    *(uint2*)(tw + q32 * 128 + phys * 4) = pkb.dw;
                }
#pragma unroll
            for (int pass = 0; pass < 8; pass++) {
                int q32 = pass * 4 + (lane >> 4);
                int p = l15;
                int phys = (p * 2) ^ ((q32 & 7) << 2);
                u32x4 val = *(const u32x4*)(tw + q32 * 128 + phys * 4);
                int qg = qt * 128 + wl * 32 + q32;
                *(u32x4*)(attn + (row0 + qg) * (size_t)DIM + h * HD + p * 8) = val;
            }
        }
        __syncthreads();
    }
}

extern "C" void kernel_launch(void* const* d_in, const int* in_sizes, int n_in,
                              void* d_out, int out_size, void* d_ws, size_t ws_size,
                              hipStream_t stream) {
    const float* x  = (const float*)d_in[0];
    const float* wq = (const float*)d_in[2];
    const float* wk = (const float*)d_in[3];
    const float* wv = (const float*)d_in[4];
    const float* wo = (const float*)d_in[5];
    float* out = (float*)d_out;

    char* ws = (char*)d_ws;
    __hip_bfloat16* xb    = (__hip_bfloat16*)(ws);                 // 4096x2048 (16MB)
    __hip_bfloat16* attn  = (__hip_bfloat16*)(ws);                 // reuses xb after QKV GEMM
    __hip_bfloat16* wqkvb = (__hip_bfloat16*)(ws + 16777216ull);   // 6144x2048 (24MB)
    __hip_bfloat16* wob   = (__hip_bfloat16*)(ws + 41943040ull);   // 2048x2048 (8MB)
    __hip_bfloat16* qkv   = (__hip_bfloat16*)(ws + 50331648ull);   // 4096x6144 (48MB; V cols unused)
    _Float16*       vtg   = (_Float16*)(ws + 100663296ull);        // 32x128x2048 f16 (16MB)

    const int nv = (BATCH * SEQ * DIM + 4 * DIM * DIM) / 4;
    cast_all<<<nv / 256, 256, 0, stream>>>(x, wq, wk, wv, wo, xb, wqkvb, wob);

    // QKV = xb @ wqkvb^T, 256x256 8-phase kernel, fused RoPE (Q,K) + V-transpose
    gemm256_qkv<<<dim3(QKVN / 256, (BATCH * SEQ) / 256), 512, 0, stream>>>(
        xb, wqkvb, qkv, vtg);

    flash_kernel<<<dim3(8, BATCH * NH), 512, 0, stream>>>(qkv, vtg, attn);

    // out = attn @ wo^T : M=4096, N=2048, K=2048 (fp32 out)
    gemm_bt<0, float><<<dim3(DIM / 128, (BATCH * SEQ) / 128), 256, 0, stream>>>(
        attn, wob, out, nullptr, BATCH * SEQ, DIM, DIM);
}

// Round 4
// 414.387 us; speedup vs baseline: 1.1198x; 1.1193x over previous
//
#include <hip/hip_runtime.h>
#include <hip/hip_bf16.h>
#include <math.h>

#define DIM   2048
#define NH    16
#define HD    128
#define SEQ   2048
#define BATCH 2
#define QKVN  6144   // 3*DIM

typedef __attribute__((ext_vector_type(8))) short short8;
typedef __attribute__((ext_vector_type(4))) float f32x4;
typedef __attribute__((ext_vector_type(4))) unsigned int u32x4;
typedef __attribute__((ext_vector_type(4))) _Float16 half4;

static __device__ __forceinline__ unsigned short f2bf(float f) {
    __hip_bfloat16 h = __float2bfloat16(f);
    return *reinterpret_cast<unsigned short*>(&h);
}

// async global->LDS, 16B per lane; LDS dest = base + lane*16 (wave-uniform base)
static __device__ __forceinline__ void gload16(const void* g, void* l) {
    __builtin_amdgcn_global_load_lds(
        (const __attribute__((address_space(1))) void*)(g),
        (__attribute__((address_space(3))) void*)(l), 16, 0, 0);
}

__device__ __forceinline__ void storeC_helper(float* C, size_t idx, float v) { C[idx] = v; }
__device__ __forceinline__ void storeC_helper(__hip_bfloat16* C, size_t idx, float v) { C[idx] = __float2bfloat16(v); }

// ---- scheduling primitives for the 8-phase GEMM (raw barriers, counted waits) ----
#define GFENCE()  asm volatile("" ::: "memory")
#define GBAR()    do { GFENCE(); __builtin_amdgcn_s_barrier(); GFENCE(); } while (0)
// rule #18: sched_barrier(0) after inline-asm lgkmcnt so MFMAs can't hoist above it
#define GWAITL0() do { asm volatile("s_waitcnt lgkmcnt(0)" ::: "memory"); __builtin_amdgcn_sched_barrier(0); } while (0)
#define GWAITV(n) asm volatile("s_waitcnt vmcnt(" n ")" ::: "memory")

// ---------------- fused cast fp32 -> bf16 (x + 4 weights, one launch) ----------------
__global__ __launch_bounds__(256) void cast_all(const float* __restrict__ x,
                                                const float* __restrict__ wq,
                                                const float* __restrict__ wk,
                                                const float* __restrict__ wv,
                                                const float* __restrict__ wo,
                                                __hip_bfloat16* __restrict__ xb,
                                                __hip_bfloat16* __restrict__ wqkvb,
                                                __hip_bfloat16* __restrict__ wob) {
    const int VX = (BATCH * SEQ * DIM) / 4;
    const int VW = (DIM * DIM) / 4;
    int v = blockIdx.x * blockDim.x + threadIdx.x;
    const float* src; __hip_bfloat16* dst; int off;
    if (v < VX)               { src = x;  dst = xb;                            off = v; }
    else if (v < VX + VW)     { src = wq; dst = wqkvb;                         off = v - VX; }
    else if (v < VX + 2 * VW) { src = wk; dst = wqkvb + (size_t)DIM * DIM;     off = v - VX - VW; }
    else if (v < VX + 3 * VW) { src = wv; dst = wqkvb + 2ull * DIM * DIM;      off = v - VX - 2 * VW; }
    else                      { src = wo; dst = wob;                           off = v - VX - 3 * VW; }
    float4 f = *(const float4*)(src + (size_t)off * 4);
    union { unsigned short u[4]; uint2 d; } pk;
    pk.u[0] = f2bf(f.x); pk.u[1] = f2bf(f.y); pk.u[2] = f2bf(f.z); pk.u[3] = f2bf(f.w);
    *(uint2*)(dst + (size_t)off * 4) = pk.d;
}

// ---------------- 256x256 8-phase bf16 GEMM (QKV, fused RoPE + V-transpose) ----------
// C[m,n] = sum_k A[m,k]*B[n,k], M=4096, N=6144, K=2048.
// 512 thr = 8 waves (2M x 4N); per-wave out 128x64 (acc[8][4] in AGPRs); BK=64.
// r4 register plan (fix for r2/r3 spill: 96 live frag VGPRs -> 48):
//   PHASE-LOCAL reads: each phase reads only its own cluster's operands
//   (8 or 4 ds_read_b128), consumed right after lgkmcnt(0).
//   p1: aQ0kk0+bkk0 (8), p2: aQ1kk0 (4), p3: aQ0kk1+bkk1 (8), p4: aQ1kk1 (4).
// Stage plan: tile 2i+1 -> buf1 at p1(h2+h3) p2(h0) p3(h1), gate vmcnt(0) @p4-end
// (last loads ~2 phases old); tile 2i+2 -> buf0 at p5(h2+h3) p6(h0) p7(h1),
// gate vmcnt(0) @p8-end. WAR-safe: each staged region's last reader drained
// >=2 barriers before the stage. setprio(1) wraps each 16-MFMA cluster.
template <int MOFF>
static __device__ __forceinline__ void mfma16(const short8 (&af)[4], const short8 (&bf)[4],
                                              f32x4 (&acc)[8][4]) {
    __builtin_amdgcn_s_setprio(1);
#pragma unroll
    for (int mt = 0; mt < 4; mt++)
#pragma unroll
        for (int nt = 0; nt < 4; nt++)
            acc[MOFF + mt][nt] = __builtin_amdgcn_mfma_f32_16x16x32_bf16(
                af[mt], bf[nt], acc[MOFF + mt][nt], 0, 0, 0);
    __builtin_amdgcn_s_setprio(0);
}

__global__ __attribute__((amdgpu_waves_per_eu(2, 2))) __launch_bounds__(512)
void gemm256_qkv(const __hip_bfloat16* __restrict__ A,
                 const __hip_bfloat16* __restrict__ B,
                 __hip_bfloat16* __restrict__ C,
                 _Float16* __restrict__ vt) {
    constexpr int K  = DIM;       // 2048
    constexpr int N  = QKVN;      // 6144
    constexpr int NT = K / 64;    // 32 K-tiles
    constexpr int NI = NT / 2;    // 16 iterations
    __shared__ __align__(16) __hip_bfloat16 As[2][256 * 64];   // 64KB
    __shared__ __align__(16) __hip_bfloat16 Bs[2][256 * 64];   // 64KB

    int tid  = threadIdx.x;
    int lane = tid & 63;
    int wave = tid >> 6;
    int wm   = wave >> 2;      // 0..1  (M half)
    int wn   = wave & 3;       // 0..3  (N quarter)
    int quad = lane >> 4;
    int l15  = lane & 15;
    int m0   = blockIdx.y * 256;
    int n0   = blockIdx.x * 256;

    f32x4 acc[8][4] = {};

    // half-tile stage: h=0,1 -> A rows h*128.., h=2,3 -> B rows (h-2)*128..
    // LDS linear dest; source chunk pre-swizzled so reads use phys = c ^ (row&7).
    auto stage = [&](int tau, int h) {
        const __hip_bfloat16* src;
        __hip_bfloat16* dst;
        if (h < 2) { src = A + (size_t)(m0 + h * 128) * K + tau * 64;
                     dst = &As[tau & 1][h * 8192]; }
        else       { src = B + (size_t)(n0 + (h - 2) * 128) * K + tau * 64;
                     dst = &Bs[tau & 1][(h - 2) * 8192]; }
#pragma unroll
        for (int c = 0; c < 2; c++) {
            int br = (wave * 2 + c) * 8;
            int r  = br + (lane >> 3);
            int cc = (lane & 7) ^ (r & 7);
            gload16(src + (size_t)r * K + cc * 8, dst + br * 64);
        }
    };

    // per-thread constant fragment bases (row&7 == l15&7 for all mt/nt)
    int swz = l15 & 7;
    const __hip_bfloat16* a00 = &As[0][(wm * 128 + l15) * 64 + ((quad    ) ^ swz) * 8]; // kk0
    const __hip_bfloat16* a01 = &As[0][(wm * 128 + l15) * 64 + ((4 + quad) ^ swz) * 8]; // kk1
    const __hip_bfloat16* b00 = &Bs[0][(wn * 64  + l15) * 64 + ((quad    ) ^ swz) * 8];
    const __hip_bfloat16* b01 = &Bs[0][(wn * 64  + l15) * 64 + ((4 + quad) ^ swz) * 8];

    short8 fa[4], fb[4];

    // ---- prologue: tile0 fully staged, drained, barrier
    stage(0, 0); stage(0, 1); stage(0, 2); stage(0, 3);
    GWAITV("0");
    GBAR();

#pragma unroll 1
    for (int i = 0; i < NI; i++) {
        const bool nl = (i < NI - 1);
        // ================= tile 2i (buf0), phases 1-4 =================
        // p1: stage T1 h2+h3; read aQ0kk0 + bkk0; MFMA Q0 x kk0
        stage(2 * i + 1, 2); stage(2 * i + 1, 3);
#pragma unroll
        for (int t = 0; t < 4; t++) fa[t] = *(const short8*)(a00 + t * 1024);
#pragma unroll
        for (int t = 0; t < 4; t++) fb[t] = *(const short8*)(b00 + t * 1024);
        GBAR(); GWAITL0(); mfma16<0>(fa, fb, acc); GBAR();
        // p2: stage T1 h0; read aQ1kk0; MFMA Q1 x kk0 (fb=bkk0 still live)
        stage(2 * i + 1, 0);
#pragma unroll
        for (int t = 0; t < 4; t++) fa[t] = *(const short8*)(a00 + (4 + t) * 1024);
        GBAR(); GWAITL0(); mfma16<4>(fa, fb, acc); GBAR();
        // p3: stage T1 h1; read aQ0kk1 + bkk1; MFMA Q0 x kk1
        stage(2 * i + 1, 1);
#pragma unroll
        for (int t = 0; t < 4; t++) fa[t] = *(const short8*)(a01 + t * 1024);
#pragma unroll
        for (int t = 0; t < 4; t++) fb[t] = *(const short8*)(b01 + t * 1024);
        GBAR(); GWAITL0(); mfma16<0>(fa, fb, acc); GBAR();
        // p4: read aQ1kk1; MFMA Q1 x kk1; gate ALL of T1 (vmcnt 0, ~2-phase lead)
#pragma unroll
        for (int t = 0; t < 4; t++) fa[t] = *(const short8*)(a01 + (4 + t) * 1024);
        GBAR(); GWAITL0(); mfma16<4>(fa, fb, acc);
        GWAITV("0");
        GBAR();
        // ================= tile 2i+1 (buf1), phases 5-8 =================
        // p5: stage T2 h2+h3; read aQ0kk0 + bkk0 (buf1); MFMA Q0 x kk0
        if (nl) { stage(2 * i + 2, 2); stage(2 * i + 2, 3); }
#pragma unroll
        for (int t = 0; t < 4; t++) fa[t] = *(const short8*)(a00 + 16384 + t * 1024);
#pragma unroll
        for (int t = 0; t < 4; t++) fb[t] = *(const short8*)(b00 + 16384 + t * 1024);
        GBAR(); GWAITL0(); mfma16<0>(fa, fb, acc); GBAR();
        // p6: stage T2 h0; read aQ1kk0; MFMA Q1 x kk0
        if (nl) stage(2 * i + 2, 0);
#pragma unroll
        for (int t = 0; t < 4; t++) fa[t] = *(const short8*)(a00 + 16384 + (4 + t) * 1024);
        GBAR(); GWAITL0(); mfma16<4>(fa, fb, acc); GBAR();
        // p7: stage T2 h1; read aQ0kk1 + bkk1; MFMA Q0 x kk1
        if (nl) stage(2 * i + 2, 1);
#pragma unroll
        for (int t = 0; t < 4; t++) fa[t] = *(const short8*)(a01 + 16384 + t * 1024);
#pragma unroll
        for (int t = 0; t < 4; t++) fb[t] = *(const short8*)(b01 + 16384 + t * 1024);
        GBAR(); GWAITL0(); mfma16<0>(fa, fb, acc); GBAR();
        // p8: read aQ1kk1; MFMA Q1 x kk1; gate ALL of T2 (vmcnt 0)
#pragma unroll
        for (int t = 0; t < 4; t++) fa[t] = *(const short8*)(a01 + 16384 + (4 + t) * 1024);
        GBAR(); GWAITL0(); mfma16<4>(fa, fb, acc);
        if (nl) GWAITV("0");
        GBAR();
    }

    // ---------------- epilogue (block-uniform branch: n0 aligned to 256) ----------------
    int ncol0 = n0 + wn * 64;
    if (ncol0 >= 4096) {
        // V: transpose per-wave 128(s) x 64(d) via private 16KB LDS region, store f16
        _Float16* T = ((wave < 4) ? (_Float16*)As : (_Float16*)Bs) + (wave & 3) * 8192;
#pragma unroll
        for (int mt = 0; mt < 8; mt++)
#pragma unroll
            for (int nt = 0; nt < 4; nt++) {
                half4 hv;
#pragma unroll
                for (int r = 0; r < 4; r++) hv[r] = (_Float16)acc[mt][nt][r];
                int chunk = mt * 2 + (quad >> 1);       // s>>3
                int phys  = chunk ^ l15;                // ^ (d&15), d = nt*16+l15
                *(half4*)(T + (nt * 16 + l15) * 128 + phys * 8 + (quad & 1) * 4) = hv;
            }
        int h  = (ncol0 - 4096) >> 7;
        int d0 = (ncol0 - 4096) & 127;                  // 0 or 64
        int b  = (m0 + wm * 128) >> 11;
        int sb = (m0 + wm * 128) & (SEQ - 1);
#pragma unroll
        for (int pass = 0; pass < 16; pass++) {
            int d = pass * 4 + quad;
            int phys = l15 ^ (d & 15);
            u32x4 val = *(const u32x4*)(T + d * 128 + phys * 8);
            *(u32x4*)(vt + ((size_t)((b * NH + h) * HD + d0 + d)) * SEQ + sb + l15 * 8) = val;
        }
    } else {
        // Q,K: fused RoPE + bf16 store
#pragma unroll
        for (int nt = 0; nt < 4; nt++) {
            int col = ncol0 + nt * 16 + l15;
            float theta = __expf(-((float)((col & 127) & ~1) * (1.0f / (float)HD)) * 9.210340371976184f);
#pragma unroll
            for (int mt = 0; mt < 8; mt++)
#pragma unroll
                for (int r = 0; r < 4; r++) {
                    int row = m0 + wm * 128 + mt * 16 + quad * 4 + r;
                    float val = acc[mt][nt][r];
                    float part = __shfl_xor(val, 1);
                    int s = row & (SEQ - 1);
                    float sn, cs;
                    __sincosf((float)s * theta, &sn, &cs);
                    val = (l15 & 1) ? val * cs + part * sn : val * cs - part * sn;
                    C[(size_t)row * N + col] = __float2bfloat16(val);
                }
        }
    }
}

// ---------------- bf16 GEMM, C[m,n] = sum_k A[m,k]*B[n,k] (128x128, out-proj) --------
template <int MODE, typename OutT>
__global__ __launch_bounds__(256) void gemm_bt(const __hip_bfloat16* __restrict__ A,
                                               const __hip_bfloat16* __restrict__ B,
                                               OutT* __restrict__ C,
                                               _Float16* __restrict__ vt,
                                               int M, int N, int K) {
    constexpr int BK = 64;
    __shared__ __align__(16) __hip_bfloat16 As[128 * BK];
    __shared__ __align__(16) __hip_bfloat16 Bs[128 * BK];
    int tid  = threadIdx.x;
    int lane = tid & 63;
    int wave = tid >> 6;
    int quad = lane >> 4;
    int l15  = lane & 15;
    int wr   = wave >> 1, wc = wave & 1;
    int m0 = blockIdx.y * 128;
    int n0 = blockIdx.x * 128;
    f32x4 acc[4][4] = {};

    for (int k0 = 0; k0 < K; k0 += BK) {
        __syncthreads();
#pragma unroll
        for (int c = 0; c < 4; c++) {
            int br = (wave * 4 + c) * 8;
            int r  = br + (lane >> 3);
            int cc = (lane & 7) ^ (r & 7);
            gload16(A + (size_t)(m0 + r) * K + k0 + cc * 8, As + br * 64);
            gload16(B + (size_t)(n0 + r) * K + k0 + cc * 8, Bs + br * 64);
        }
        __syncthreads();
#pragma unroll
        for (int kk = 0; kk < BK; kk += 32) {
            short8 af[4], bf4[4];
#pragma unroll
            for (int t = 0; t < 4; t++) {
                int Ra = wr * 64 + t * 16 + l15;
                int pa = ((kk >> 3) + quad) ^ (Ra & 7);
                af[t] = *(const short8*)(As + Ra * 64 + pa * 8);
                int Rb = wc * 64 + t * 16 + l15;
                int pb = ((kk >> 3) + quad) ^ (Rb & 7);
                bf4[t] = *(const short8*)(Bs + Rb * 64 + pb * 8);
            }
#pragma unroll
            for (int mt = 0; mt < 4; mt++)
#pragma unroll
                for (int nt = 0; nt < 4; nt++)
                    acc[mt][nt] = __builtin_amdgcn_mfma_f32_16x16x32_bf16(af[mt], bf4[nt], acc[mt][nt], 0, 0, 0);
        }
    }

#pragma unroll
    for (int nt = 0; nt < 4; nt++) {
        int col = n0 + wc * 64 + nt * 16 + l15;
#pragma unroll
        for (int mt = 0; mt < 4; mt++)
#pragma unroll
            for (int r = 0; r < 4; r++) {
                int row = m0 + wr * 64 + mt * 16 + quad * 4 + r;
                storeC_helper(C, (size_t)row * N + col, acc[mt][nt][r]);
            }
    }
}

// ---------------- flash attention (causal) ----------------
// 512 threads = 8 waves = 2 groups x 4. qtile=128 (wave owns 32 q-rows).
// Group g processes half the key range; online-softmax partials merged in LDS.
// Pairs (i,15-i): every block 17+17 iters. grid (8,32)=256 blocks, 2 waves/SIMD.
// S^T = K·Q^T so P exits in B-operand layout for 16x16x16 f16 PV.
__global__ __launch_bounds__(512, 2) void flash_kernel(const __hip_bfloat16* __restrict__ qkv,
                                                       const _Float16* __restrict__ vt,
                                                       __hip_bfloat16* __restrict__ attn) {
    __shared__ __align__(16) __hip_bfloat16 Ks[2][2][64 * 128];   // [group][buf] 64KB
    __shared__ __align__(16) _Float16 Vts[2][2][128 * 64];        // [group][buf] 64KB
    int tid  = threadIdx.x;
    int lane = tid & 63;
    int wave = tid >> 6;
    int grp  = wave >> 2;
    int wl   = wave & 3;
    int quad = lane >> 4;
    int l15  = lane & 15;
    int pairi = blockIdx.x;
    int bh = blockIdx.y;
    int b  = bh >> 4;
    int h  = bh & 15;
    size_t row0 = (size_t)b * SEQ;
    const _Float16* vbase = vt + (size_t)bh * HD * SEQ;
    const float scale = 0.08838834764831845f;
    const float NEG = -1e30f;

    auto stage = [&](int buf, int kt) {
#pragma unroll
        for (int c = 0; c < 4; c++) {
            int br = (wl * 4 + c) * 4;
            int r  = br + (lane >> 4);
            int cc = (lane & 15) ^ (r & 15);
            gload16(qkv + (row0 + kt * 64 + r) * (size_t)QKVN + DIM + h * HD + cc * 8,
                    &Ks[grp][buf][br * 128]);
        }
#pragma unroll
        for (int c = 0; c < 4; c++) {
            int br = (wl * 4 + c) * 8;
            int r  = br + (lane >> 3);
            int cc = (lane & 7) ^ ((r >> 1) & 7);
            gload16(vbase + (size_t)r * SEQ + kt * 64 + cc * 8, &Vts[grp][buf][br * 64]);
        }
    };

    for (int seg = 0; seg < 2; seg++) {
        int qt = seg ? (15 - pairi) : pairi;
        int half = qt + 1;
        int kbase = grp ? half : 0;

        short8 qf[2][4];
#pragma unroll
        for (int mt = 0; mt < 2; mt++) {
            int qrow = qt * 128 + wl * 32 + mt * 16 + l15;
            const __hip_bfloat16* qptr = qkv + (row0 + qrow) * (size_t)QKVN + h * HD + quad * 8;
#pragma unroll
            for (int c = 0; c < 4; c++) qf[mt][c] = *(const short8*)(qptr + c * 32);
        }
        f32x4 o[2][8] = {};
        float m_[2] = {NEG, NEG}, l_[2] = {0.f, 0.f};

        stage(0, kbase);

        for (int i = 0; i < half; i++) {
            __syncthreads();
            if (i + 1 < half) stage((i + 1) & 1, kbase + i + 1);
            int kt = kbase + i;
            const __hip_bfloat16* ks = Ks[grp][i & 1];
            const _Float16* vts = Vts[grp][i & 1];

            f32x4 s[2][4] = {};
#pragma unroll
            for (int ktile = 0; ktile < 4; ktile++) {
                int R = ktile * 16 + l15;
#pragma unroll
                for (int c = 0; c < 4; c++) {
                    int phys = (c * 4 + quad) ^ (R & 15);
                    short8 kf = *(const short8*)(ks + R * 128 + phys * 8);
                    s[0][ktile] = __builtin_amdgcn_mfma_f32_16x16x32_bf16(kf, qf[0][c], s[0][ktile], 0, 0, 0);
                    s[1][ktile] = __builtin_amdgcn_mfma_f32_16x16x32_bf16(kf, qf[1][c], s[1][ktile], 0, 0, 0);
                }
            }
            bool diag = (kt >= 2 * qt);
            float alpha[2];
#pragma unroll
            for (int mt = 0; mt < 2; mt++) {
                int q = qt * 128 + wl * 32 + mt * 16 + l15;
#pragma unroll
                for (int ktile = 0; ktile < 4; ktile++)
#pragma unroll
                    for (int r = 0; r < 4; r++) {
                        float v = s[mt][ktile][r] * scale;
                        if (diag) {
                            int key = kt * 64 + ktile * 16 + quad * 4 + r;
                            if (key > q) v = NEG;
                        }
                        s[mt][ktile][r] = v;
                    }
                float v = s[mt][0][0];
#pragma unroll
                for (int ktile = 0; ktile < 4; ktile++)
#pragma unroll
                    for (int r = 0; r < 4; r++) v = fmaxf(v, s[mt][ktile][r]);
                v = fmaxf(v, __shfl_xor(v, 16));
                v = fmaxf(v, __shfl_xor(v, 32));
                float mnew = fmaxf(m_[mt], v);
                alpha[mt] = __expf(m_[mt] - mnew);
                m_[mt] = mnew;
                float sum = 0.f;
#pragma unroll
                for (int ktile = 0; ktile < 4; ktile++)
#pragma unroll
                    for (int r = 0; r < 4; r++) {
                        float p = __expf(s[mt][ktile][r] - mnew);
                        s[mt][ktile][r] = p;
                        sum += p;
                    }
                sum += __shfl_xor(sum, 16);
                sum += __shfl_xor(sum, 32);
                l_[mt] = l_[mt] * alpha[mt] + sum;
#pragma unroll
                for (int dt = 0; dt < 8; dt++) o[mt][dt] *= alpha[mt];
            }
            half4 pk[2][4];
#pragma unroll
            for (int mt = 0; mt < 2; mt++)
#pragma unroll
                for (int kc = 0; kc < 4; kc++)
#pragma unroll
                    for (int r = 0; r < 4; r++) pk[mt][kc][r] = (_Float16)s[mt][kc][r];
#pragma unroll
            for (int kc = 0; kc < 4; kc++)
#pragma unroll
                for (int dt = 0; dt < 8; dt++) {
                    int d = dt * 16 + l15;
                    int c4 = ((kc * 4 + quad) ^ (d & 14));
                    half4 vf = *(const half4*)(vts + d * 64 + c4 * 4);
                    o[0][dt] = __builtin_amdgcn_mfma_f32_16x16x16f16(vf, pk[0][kc], o[0][dt], 0, 0, 0);
                    o[1][dt] = __builtin_amdgcn_mfma_f32_16x16x16f16(vf, pk[1][kc], o[1][dt], 0, 0, 0);
                }
        }

        __syncthreads();
        float* o1mb = (float*)&Ks[0][0][0];
        float* mlmb = (float*)&Vts[0][0][0];
        __hip_bfloat16* tb = (__hip_bfloat16*)((char*)&Vts[0][0][0] + 8192);
        if (grp == 1) {
            float* dst = o1mb + wl * 4096;
#pragma unroll
            for (int mt = 0; mt < 2; mt++)
#pragma unroll
                for (int dt = 0; dt < 8; dt++)
#pragma unroll
                    for (int r = 0; r < 4; r++)
                        dst[((mt * 8 + dt) * 4 + r) * 64 + lane] = o[mt][dt][r];
            float* ml = mlmb + (wl * 64 + lane) * 4;
            ml[0] = m_[0]; ml[1] = m_[1]; ml[2] = l_[0]; ml[3] = l_[1];
        }
        __syncthreads();
        if (grp == 0) {
            const float* src = o1mb + wl * 4096;
            const float* ml = mlmb + (wl * 64 + lane) * 4;
#pragma unroll
            for (int mt = 0; mt < 2; mt++) {
                float m1 = ml[mt], l1 = ml[2 + mt];
                float mm = fmaxf(m_[mt], m1);
                float a0 = __expf(m_[mt] - mm), a1 = __expf(m1 - mm);
                float linv = 1.0f / (l_[mt] * a0 + l1 * a1);
#pragma unroll
                for (int dt = 0; dt < 8; dt++)
#pragma unroll
                    for (int r = 0; r < 4; r++)
                        o[mt][dt][r] = (o[mt][dt][r] * a0 +
                                        src[((mt * 8 + dt) * 4 + r) * 64 + lane] * a1) * linv;
            }
            __hip_bfloat16* tw = tb + wl * 4096;
#pragma unroll
            for (int mt = 0; mt < 2; mt++)
#pragma unroll
                for (int dt = 0; dt < 8; dt++) {
                    int q32 = mt * 16 + l15;
                    int c4 = dt * 4 + quad;
                    int phys = c4 ^ ((q32 & 7) << 2);
                    union { unsigned short u[4]; uint2 dw; } pkb;
#pragma unroll
                    for (int r = 0; r < 4; r++) pkb.u[r] = f2bf(o[mt][dt][r]);
                    *(uint2*)(tw + q32 * 128 + phys * 4) = pkb.dw;
                }
#pragma unroll
            for (int pass = 0; pass < 8; pass++) {
                int q32 = pass * 4 + (lane >> 4);
                int p = l15;
                int phys = (p * 2) ^ ((q32 & 7) << 2);
                u32x4 val = *(const u32x4*)(tw + q32 * 128 + phys * 4);
                int qg = qt * 128 + wl * 32 + q32;
                *(u32x4*)(attn + (row0 + qg) * (size_t)DIM + h * HD + p * 8) = val;
            }
        }
        __syncthreads();
    }
}

extern "C" void kernel_launch(void* const* d_in, const int* in_sizes, int n_in,
                              void* d_out, int out_size, void* d_ws, size_t ws_size,
                              hipStream_t stream) {
    const float* x  = (const float*)d_in[0];
    const float* wq = (const float*)d_in[2];
    const float* wk = (const float*)d_in[3];
    const float* wv = (const float*)d_in[4];
    const float* wo = (const float*)d_in[5];
    float* out = (float*)d_out;

    char* ws = (char*)d_ws;
    __hip_bfloat16* xb    = (__hip_bfloat16*)(ws);                 // 4096x2048 (16MB)
    __hip_bfloat16* attn  = (__hip_bfloat16*)(ws);                 // reuses xb after QKV GEMM
    __hip_bfloat16* wqkvb = (__hip_bfloat16*)(ws + 16777216ull);   // 6144x2048 (24MB)
    __hip_bfloat16* wob   = (__hip_bfloat16*)(ws + 41943040ull);   // 2048x2048 (8MB)
    __hip_bfloat16* qkv   = (__hip_bfloat16*)(ws + 50331648ull);   // 4096x6144 (48MB; V cols unused)
    _Float16*       vtg   = (_Float16*)(ws + 100663296ull);        // 32x128x2048 f16 (16MB)

    const int nv = (BATCH * SEQ * DIM + 4 * DIM * DIM) / 4;
    cast_all<<<nv / 256, 256, 0, stream>>>(x, wq, wk, wv, wo, xb, wqkvb, wob);

    // QKV = xb @ wqkvb^T, 256x256 8-phase kernel, fused RoPE (Q,K) + V-transpose
    gemm256_qkv<<<dim3(QKVN / 256, (BATCH * SEQ) / 256), 512, 0, stream>>>(
        xb, wqkvb, qkv, vtg);

    flash_kernel<<<dim3(8, BATCH * NH), 512, 0, stream>>>(qkv, vtg, attn);

    // out = attn @ wo^T : M=4096, N=2048, K=2048 (fp32 out)
    gemm_bt<0, float><<<dim3(DIM / 128, (BATCH * SEQ) / 128), 256, 0, stream>>>(
        attn, wob, out, nullptr, BATCH * SEQ, DIM, DIM);
}